// Round 5
// baseline (610.515 us; speedup 1.0000x reference)
//
#include <hip/hip_runtime.h>
#include <math.h>

#define D_MODEL 512
#define SEQ     4096
#define BATCH   4
#define BS      (BATCH * SEQ)  // 16384

// Diagnostic: repeat each kernel's idempotent body REPS times so every
// dispatch ranks above the ~44us harness fills in the rocprof top-5 and
// exposes per-kernel counters. True per-kernel cost = row_dur / REPS.
#define REPS 5

typedef __attribute__((ext_vector_type(8))) short  short8;   // 8 x bf16 (4 VGPRs)
typedef __attribute__((ext_vector_type(4))) float  float4v;  // MFMA C/D

#define GAS __attribute__((address_space(1)))
#define LAS __attribute__((address_space(3)))

__device__ __forceinline__ void gld_lds16(const void* g, void* l) {
  __builtin_amdgcn_global_load_lds((const GAS unsigned int*)g,
                                   (LAS unsigned int*)l, 16, 0, 0);
}

__device__ __forceinline__ unsigned short bf16r(float f) {
  unsigned int u = __builtin_bit_cast(unsigned int, f);
  u += 0x7fffu + ((u >> 16) & 1u);  // RTNE
  return (unsigned short)(u >> 16);
}

__device__ __forceinline__ uint4 pack8(float4 a, float4 b) {
  uint4 o;
  o.x = bf16r(a.x) | ((unsigned)bf16r(a.y) << 16);
  o.y = bf16r(a.z) | ((unsigned)bf16r(a.w) << 16);
  o.z = bf16r(b.x) | ((unsigned)bf16r(b.y) << 16);
  o.w = bf16r(b.z) | ((unsigned)bf16r(b.w) << 16);
  return o;
}

// --------------------------------------------------------------------------
// Prep kernel:
//   blocks 0..63   : W_qk [k][n] -> Wqkt [n][k] bf16 (tile transpose)
//   blocks 64..191 : W_v straight convert to bf16
//   blocks 192..   : x fp32 -> xb bf16
// --------------------------------------------------------------------------
__global__ __launch_bounds__(256) void cvt_w(const float* __restrict__ Wqk,
                                             unsigned short* __restrict__ Wqkt,
                                             const float* __restrict__ Wv,
                                             unsigned short* __restrict__ Wvb,
                                             const float* __restrict__ x,
                                             unsigned short* __restrict__ xb) {
  __shared__ float tile[64][65];
#pragma unroll 1
  for (int rep = 0; rep < REPS; ++rep) {
    asm volatile("" ::: "memory");
    if (blockIdx.x < 64) {
      const int bx = blockIdx.x & 7;   // n-tile
      const int by = blockIdx.x >> 3;  // k-tile
      const int tx = threadIdx.x & 63;
      const int ty = threadIdx.x >> 6;
      for (int r = ty; r < 64; r += 4)
        tile[r][tx] = Wqk[(size_t)(by * 64 + r) * D_MODEL + bx * 64 + tx];
      __syncthreads();
      for (int r = ty; r < 64; r += 4)
        Wqkt[(size_t)(bx * 64 + r) * D_MODEL + by * 64 + tx] = bf16r(tile[tx][r]);
      __syncthreads();  // rep-safety: reads done before next rep's writes
    } else if (blockIdx.x < 192) {
      const int idx = ((blockIdx.x - 64) * 256 + threadIdx.x) * 8;
      const float4 a = *(const float4*)(Wv + idx);
      const float4 b = *(const float4*)(Wv + idx + 4);
      *(uint4*)(Wvb + idx) = pack8(a, b);
    } else {
      const size_t idx = ((size_t)(blockIdx.x - 192) * 256 + threadIdx.x) * 8;
      const float4 a = *(const float4*)(x + idx);
      const float4 b = *(const float4*)(x + idx + 4);
      *(uint4*)(xb + idx) = pack8(a, b);
    }
  }
}

// --------------------------------------------------------------------------
// Combined Q+V GEMM: M=16384 (x rows), N=1024 ([512 Q-cols | 512 V-dims]),
// K=512. BM=BN=256, 256 blocks (1/CU), 512 threads = 8 waves, wave-tile
// 64x128. Double-buffered LDS (2 x 64 KB), 2-phase prefetch.
// T2 source-swizzle: LDS slot s of row r holds source col-group s^(r&7);
// reads use slot (kc*4+q)^(c&7).
// --------------------------------------------------------------------------
__global__ __launch_bounds__(512, 1) void qv_gemm(const unsigned short* __restrict__ xb,
                                                  const unsigned short* __restrict__ Wqkt,
                                                  const unsigned short* __restrict__ Wvb,
                                                  const float* __restrict__ bv,
                                                  unsigned short* __restrict__ Qb,
                                                  unsigned short* __restrict__ Vt,
                                                  float scale) {
  __shared__ unsigned short As[2][256 * 64];  // 2 x 32 KB
  __shared__ unsigned short Bs[2][256 * 64];  // 2 x 32 KB

  const int t    = threadIdx.x;
  const int w    = t >> 6;
  const int lane = t & 63;
  const int q    = lane >> 4;
  const int c    = lane & 15;
  const int wr   = w >> 1;   // 0..3: wave's 64-row span within the 256-tile
  const int wc   = w & 1;    // 0..1: wave's 128-col span
  const int sw   = c & 7;    // read-side swizzle key

  const int mt = blockIdx.x & 63;   // M-tile
  const int nt = blockIdx.x >> 6;   // N-tile 0..3
  const int a0 = mt * 256;          // activation row base
  const int b0 = (nt & 1) * 256;    // weight row base within its matrix
  const bool vt = (nt >= 2);
  const unsigned short* __restrict__ Wgt = vt ? Wvb : Wqkt;

  auto stage = [&](int buf, int k0) {
#pragma unroll
    for (int it = 0; it < 4; ++it) {
      const int idx = it * 512 + t;  // 0..2047
      const int r   = idx >> 3;
      const int ss  = idx & 7;
      const int ko  = k0 + ((ss ^ (r & 7)) << 3);
      gld_lds16(xb + (size_t)(a0 + r) * D_MODEL + ko, &As[buf][idx * 8]);
      gld_lds16(Wgt + (size_t)(b0 + r) * D_MODEL + ko, &Bs[buf][idx * 8]);
    }
  };

#pragma unroll 1
  for (int rep = 0; rep < REPS; ++rep) {
    asm volatile("" ::: "memory");
    float4v acc[4][8];
#pragma unroll
    for (int i = 0; i < 4; ++i)
#pragma unroll
      for (int j = 0; j < 8; ++j) acc[i][j] = (float4v){0.f, 0.f, 0.f, 0.f};

    stage(0, 0);
    __syncthreads();  // drain prologue stage

    for (int slab = 0; slab < 8; ++slab) {
      const int buf = slab & 1;
      if (slab < 7) stage(buf ^ 1, (slab + 1) * 64);  // prefetch next slab

      const unsigned short* SA = vt ? Bs[buf] : As[buf];  // A-operand source
      const unsigned short* SB = vt ? As[buf] : Bs[buf];  // B-operand source

#pragma unroll
      for (int kc = 0; kc < 2; ++kc) {
        const int slot = ((kc * 4 + q) ^ sw) * 8;
        short8 af[4], bf[8];
#pragma unroll
        for (int i = 0; i < 4; ++i)
          af[i] = *(const short8*)&SA[(wr * 64 + i * 16 + c) * 64 + slot];
#pragma unroll
        for (int j = 0; j < 8; ++j)
          bf[j] = *(const short8*)&SB[(wc * 128 + j * 16 + c) * 64 + slot];
#pragma unroll
        for (int i = 0; i < 4; ++i)
#pragma unroll
          for (int j = 0; j < 8; ++j)
            acc[i][j] = __builtin_amdgcn_mfma_f32_16x16x32_bf16(af[i], bf[j], acc[i][j], 0, 0, 0);
      }
      __syncthreads();  // drains prefetch + lds reads
    }

    if (!vt) {
      // Qb[row][col]
#pragma unroll
      for (int i = 0; i < 4; ++i)
#pragma unroll
        for (int tt = 0; tt < 4; ++tt) {
          const int row = a0 + wr * 64 + i * 16 + 4 * q + tt;
          const int cb  = nt * 256 + wc * 128;
#pragma unroll
          for (int j = 0; j < 8; ++j)
            Qb[(size_t)row * D_MODEL + cb + j * 16 + c] = bf16r(scale * acc[i][j][tt]);
        }
    } else {
      // Vt[dim][key]
#pragma unroll
      for (int i = 0; i < 4; ++i)
#pragma unroll
        for (int tt = 0; tt < 4; ++tt) {
          const int dim = (nt - 2) * 256 + wr * 64 + i * 16 + 4 * q + tt;
          const float bvv = bv[dim];
          const int kb  = a0 + wc * 128;
#pragma unroll
          for (int j = 0; j < 8; ++j)
            Vt[(size_t)dim * BS + kb + j * 16 + c] = bf16r(acc[i][j][tt] + bvv);
        }
    }
  }
}

// --------------------------------------------------------------------------
// Windowed causal ALiBi attention (unchanged math). Block = 128 threads
// (2 waves) = one 16-query tile; grid = 1024. Window = keys [i0-48, i0+15].
// --------------------------------------------------------------------------
__global__ __launch_bounds__(128) void attn_tile(const unsigned short* __restrict__ Q,
                                                 const unsigned short* __restrict__ Kx,
                                                 const unsigned short* __restrict__ Vt,
                                                 float* __restrict__ out) {
  constexpr int PLD = 72;  // 64 + 8 pad shorts; row stride 144 B (16B-aligned)
  __shared__ unsigned short pls[16 * PLD];  // 2304 B
  __shared__ float lm[2][16], ls[2][16];

  const int t    = threadIdx.x;
  const int h    = t >> 6;
  const int lane = t & 63;
  const int q    = lane >> 4;
  const int c    = lane & 15;

  // XCD-contiguous swizzle: XCD x gets tiles [x*128, (x+1)*128)
  const int tile = ((blockIdx.x & 7) << 7) + (blockIdx.x >> 3);
  const int r0   = tile << 4;           // global query base
  const int b    = r0 >> 12;            // batch
  const int i0   = r0 & (SEQ - 1);      // local query base
  const int jb   = i0 - 48;             // window start (may be < 0)

#pragma unroll 1
  for (int rep = 0; rep < REPS; ++rep) {
    asm volatile("" ::: "memory");

    // ---- Q fragments ----
    short8 qf[16];
    {
      const unsigned short* qp = Q + (size_t)(r0 + c) * D_MODEL + q * 8;
#pragma unroll
      for (int ch = 0; ch < 16; ++ch) qf[ch] = *(const short8*)(qp + ch * 32);
    }

    // ---- S = Q K^T for this wave's 2 subtiles (sj = 2h, 2h+1) ----
    float4v sacc[2];
    sacc[0] = (float4v){0.f, 0.f, 0.f, 0.f};
    sacc[1] = (float4v){0.f, 0.f, 0.f, 0.f};
#pragma unroll
    for (int s = 0; s < 2; ++s) {
      const int sj = 2 * h + s;
      if (jb + 16 * sj + 15 < 0) continue;  // whole subtile below key 0
      int krow = jb + 16 * sj + c;
      if (krow < 0) krow = 0;  // masked below
      const unsigned short* kr = Kx + ((size_t)(b << 12) + krow) * D_MODEL + q * 8;
      float4v sv = sacc[s];
#pragma unroll
      for (int ch = 0; ch < 16; ++ch)
        sv = __builtin_amdgcn_mfma_f32_16x16x32_bf16(qf[ch], *(const short8*)(kr + ch * 32), sv, 0, 0, 0);
      sacc[s] = sv;
    }

    // ---- prefetch V chunk 0 ----
    const unsigned short* vbase = Vt + (size_t)(h * 256 + c) * BS + (b << 12);
    const bool ch0 = (jb + 31 >= 0);
    short8 vf0[16];
    if (ch0) {
      int kk = jb + q * 8;
      if (kk < 0) kk = 0;  // p == 0 there
      const unsigned short* vb = vbase + kk;
#pragma unroll
      for (int dt = 0; dt < 16; ++dt) vf0[dt] = *(const short8*)(vb + (size_t)dt * 16 * BS);
    }

    // ---- ALiBi + causal/window mask + wave-local row max ----
    float tmax[4] = {-1e30f, -1e30f, -1e30f, -1e30f};
#pragma unroll
    for (int s = 0; s < 2; ++s)
#pragma unroll
      for (int tt = 0; tt < 4; ++tt) {
        const int jl = jb + 16 * (2 * h + s) + c;
        const int il = i0 + 4 * q + tt;
        float sv = sacc[s][tt];
        sv = (jl < 0 || jl > il) ? -1e30f : sv + 0.5f * (float)(jl - il);
        sacc[s][tt] = sv;
        tmax[tt] = fmaxf(tmax[tt], sv);
      }
#pragma unroll
    for (int tt = 0; tt < 4; ++tt) {
      float v = tmax[tt];
      v = fmaxf(v, __shfl_xor(v, 1, 64));
      v = fmaxf(v, __shfl_xor(v, 2, 64));
      v = fmaxf(v, __shfl_xor(v, 4, 64));
      v = fmaxf(v, __shfl_xor(v, 8, 64));
      tmax[tt] = v;
    }
    if (c == 0) {
#pragma unroll
      for (int tt = 0; tt < 4; ++tt) lm[h][4 * q + tt] = tmax[tt];
    }
    __syncthreads();  // 2-wave barrier (also drains vf0 prefetch)

    // ---- global max, p = exp(s-m), P -> LDS, partial sums ----
    float m[4];
#pragma unroll
    for (int tt = 0; tt < 4; ++tt)
      m[tt] = fmaxf(lm[0][4 * q + tt], lm[1][4 * q + tt]);

    float rsum[4] = {0.f, 0.f, 0.f, 0.f};
#pragma unroll
    for (int s = 0; s < 2; ++s)
#pragma unroll
      for (int tt = 0; tt < 4; ++tt) {
        const float p = __expf(sacc[s][tt] - m[tt]);
        rsum[tt] += p;
        pls[(4 * q + tt) * PLD + (2 * h + s) * 16 + c] = bf16r(p);
      }
#pragma unroll
    for (int tt = 0; tt < 4; ++tt) {
      float v = rsum[tt];
      v += __shfl_xor(v, 1, 64);
      v += __shfl_xor(v, 2, 64);
      v += __shfl_xor(v, 4, 64);
      v += __shfl_xor(v, 8, 64);
      rsum[tt] = v;
    }
    if (c == 0) {
#pragma unroll
      for (int tt = 0; tt < 4; ++tt) ls[h][4 * q + tt] = rsum[tt];
    }
    __syncthreads();  // 2-wave barrier

    float l[4];
#pragma unroll
    for (int tt = 0; tt < 4; ++tt)
      l[tt] = ls[0][4 * q + tt] + ls[1][4 * q + tt];

    // ---- O = P V for D-half h (dims h*256 .. +255), 64 keys ----
    float4v oacc[16];
#pragma unroll
    for (int dt = 0; dt < 16; ++dt) oacc[dt] = (float4v){0.f, 0.f, 0.f, 0.f};

    if (ch0) {
      const short8 pa = *(const short8*)&pls[c * PLD + q * 8];
#pragma unroll
      for (int dt = 0; dt < 16; ++dt)
        oacc[dt] = __builtin_amdgcn_mfma_f32_16x16x32_bf16(pa, vf0[dt], oacc[dt], 0, 0, 0);
    }
    {
      const short8 pa = *(const short8*)&pls[c * PLD + 32 + q * 8];
      int kk = jb + 32 + q * 8;
      if (kk < 0) kk = 0;  // p == 0 there
      const unsigned short* vb = vbase + kk;
#pragma unroll
      for (int dt = 0; dt < 16; ++dt) {
        const short8 vf = *(const short8*)(vb + (size_t)dt * 16 * BS);
        oacc[dt] = __builtin_amdgcn_mfma_f32_16x16x32_bf16(pa, vf, oacc[dt], 0, 0, 0);
      }
    }

    // ---- epilogue: O / l ----
    float inv[4];
#pragma unroll
    for (int tt = 0; tt < 4; ++tt) inv[tt] = 1.0f / l[tt];
#pragma unroll
    for (int dt = 0; dt < 16; ++dt)
#pragma unroll
      for (int tt = 0; tt < 4; ++tt)
        out[(size_t)(r0 + 4 * q + tt) * D_MODEL + h * 256 + dt * 16 + c] =
            oacc[dt][tt] * inv[tt];
  }
}

// --------------------------------------------------------------------------
extern "C" void kernel_launch(void* const* d_in, const int* in_sizes, int n_in,
                              void* d_out, int out_size, void* d_ws,
                              size_t ws_size, hipStream_t stream) {
  const float* x   = (const float*)d_in[0];
  const float* Wqk = (const float*)d_in[1];
  const float* Wv  = (const float*)d_in[2];
  const float* bv  = (const float*)d_in[3];
  float* out = (float*)d_out;

  unsigned short* xb   = (unsigned short*)d_ws;                  // 16 MB
  unsigned short* Qb   = xb + (size_t)BS * D_MODEL;              // 16 MB
  unsigned short* Vt   = Qb + (size_t)BS * D_MODEL;              // 16 MB
  unsigned short* Wqkt = Vt + (size_t)BS * D_MODEL;              // 512 KB
  unsigned short* Wvb  = Wqkt + (size_t)D_MODEL * D_MODEL;       // 512 KB

  const float scale = 1.0f / sqrtf((float)D_MODEL);

  cvt_w<<<dim3(192 + (BS * D_MODEL / 2048)), dim3(256), 0, stream>>>(Wqk, Wqkt, Wv, Wvb, x, xb);
  qv_gemm<<<dim3(256), dim3(512), 0, stream>>>(xb, Wqkt, Wvb, bv, Qb, Vt, scale);
  attn_tile<<<dim3(BS / 16), dim3(128), 0, stream>>>(Qb, xb, Vt, out);
}

// Round 6
// 132.219 us; speedup vs baseline: 4.6175x; 4.6175x over previous
//
#include <hip/hip_runtime.h>
#include <math.h>

#define D_MODEL 512
#define SEQ     4096
#define BATCH   4
#define BS      (BATCH * SEQ)  // 16384

typedef __attribute__((ext_vector_type(8))) short  short8;   // 8 x bf16 (4 VGPRs)
typedef __attribute__((ext_vector_type(4))) float  float4v;  // MFMA C/D

#define GAS __attribute__((address_space(1)))
#define LAS __attribute__((address_space(3)))

__device__ __forceinline__ void gld_lds16(const void* g, void* l) {
  __builtin_amdgcn_global_load_lds((const GAS unsigned int*)g,
                                   (LAS unsigned int*)l, 16, 0, 0);
}

__device__ __forceinline__ unsigned short bf16r(float f) {
  unsigned int u = __builtin_bit_cast(unsigned int, f);
  u += 0x7fffu + ((u >> 16) & 1u);  // RTNE
  return (unsigned short)(u >> 16);
}

__device__ __forceinline__ uint4 pack8(float4 a, float4 b) {
  uint4 o;
  o.x = bf16r(a.x) | ((unsigned)bf16r(a.y) << 16);
  o.y = bf16r(a.z) | ((unsigned)bf16r(a.w) << 16);
  o.z = bf16r(b.x) | ((unsigned)bf16r(b.y) << 16);
  o.w = bf16r(b.z) | ((unsigned)bf16r(b.w) << 16);
  return o;
}

// --------------------------------------------------------------------------
// Prep kernel:
//   blocks 0..63   : W_qk [k][n] -> Wqkt [n][k] bf16 (tile transpose)
//   blocks 64..191 : W_v straight convert to bf16
//   blocks 192..   : x fp32 -> xb bf16
// --------------------------------------------------------------------------
__global__ __launch_bounds__(256) void cvt_w(const float* __restrict__ Wqk,
                                             unsigned short* __restrict__ Wqkt,
                                             const float* __restrict__ Wv,
                                             unsigned short* __restrict__ Wvb,
                                             const float* __restrict__ x,
                                             unsigned short* __restrict__ xb) {
  if (blockIdx.x < 64) {
    __shared__ float tile[64][65];
    const int bx = blockIdx.x & 7;   // n-tile
    const int by = blockIdx.x >> 3;  // k-tile
    const int tx = threadIdx.x & 63;
    const int ty = threadIdx.x >> 6;
    for (int r = ty; r < 64; r += 4)
      tile[r][tx] = Wqk[(size_t)(by * 64 + r) * D_MODEL + bx * 64 + tx];
    __syncthreads();
    for (int r = ty; r < 64; r += 4)
      Wqkt[(size_t)(bx * 64 + r) * D_MODEL + by * 64 + tx] = bf16r(tile[tx][r]);
  } else if (blockIdx.x < 192) {
    const int idx = ((blockIdx.x - 64) * 256 + threadIdx.x) * 8;
    const float4 a = *(const float4*)(Wv + idx);
    const float4 b = *(const float4*)(Wv + idx + 4);
    *(uint4*)(Wvb + idx) = pack8(a, b);
  } else {
    const size_t idx = ((size_t)(blockIdx.x - 192) * 256 + threadIdx.x) * 8;
    const float4 a = *(const float4*)(x + idx);
    const float4 b = *(const float4*)(x + idx + 4);
    *(uint4*)(xb + idx) = pack8(a, b);
  }
}

// --------------------------------------------------------------------------
// Combined Q+V GEMM, m97-proven geometry. M=16384, N=1024 (4 Q-col tiles |
// 4 V-dim tiles), K=512. BM=BN=128, BK=64, 1024 blocks x 256 threads
// (4 waves, wave-tile 64x64), SINGLE-buffered 32 KB LDS,
// __launch_bounds__(256,4) -> VGPR<=128 -> 4 blocks/CU co-resident:
// one block's MFMA hides another's staging drain (the round-5 counters
// showed 1 block/CU serializing on the per-slab vmcnt(0) drain:
// MfmaUtil 8.5%, HBM 24%, occ 17%).
// Grid: mt fastest (bid&127) -> the 8 blocks sharing an A-panel differ by
// 128 (== 0 mod 8) -> same XCD -> A-panel L2-resident. Per-XCD working
// set ~3 MB < 4 MB L2.
// Operand order per path chosen so acc's 4 tt-values are CONTIGUOUS in the
// output -> packed 8B stores (round 5: 2B scalar stores caused 2x HBM
// write amplification, 67 vs 32 MB):
//   Q-path swapped  (A=W, B=x): D[wcol][xrow]; tt spans Q-cols.
//   V-path unswapped(A=x, B=W): D[key][dim];  tt spans keys (Vt row-dir).
// T2 source-swizzle retained: LDS slot s of row r holds source col-group
// s^(r&7); reads use slot (kc*4+q)^(c&7).
// --------------------------------------------------------------------------
__global__ __launch_bounds__(256, 4) void qv_gemm(const unsigned short* __restrict__ xb,
                                                  const unsigned short* __restrict__ Wqkt,
                                                  const unsigned short* __restrict__ Wvb,
                                                  const float* __restrict__ bv,
                                                  unsigned short* __restrict__ Qb,
                                                  unsigned short* __restrict__ Vt,
                                                  float scale) {
  __shared__ unsigned short As[128 * 64];  // 16 KB (x rows)
  __shared__ unsigned short Bs[128 * 64];  // 16 KB (weight rows = out cols)

  const int t    = threadIdx.x;
  const int w    = t >> 6;
  const int lane = t & 63;
  const int q    = lane >> 4;
  const int c    = lane & 15;
  const int wr   = w >> 1;   // 0/1: wave's 64-span on the A-side (D rows)
  const int wc   = w & 1;    // 0/1: wave's 64-span on the B-side (D cols)
  const int sw   = c & 7;    // read-side swizzle key

  const int mt = blockIdx.x & 127;  // M-tile (x-row tile), fastest -> XCD share
  const int nt = blockIdx.x >> 7;   // 0..7: 0-3 Q col-tiles, 4-7 V dim-tiles
  const int a0 = mt * 128;
  const bool vt = (nt >= 4);
  const int b0 = (vt ? (nt - 4) : nt) * 128;
  const unsigned short* __restrict__ Wgt = vt ? Wvb : Wqkt;

  float4v acc[4][4];
#pragma unroll
  for (int i = 0; i < 4; ++i)
#pragma unroll
    for (int j = 0; j < 4; ++j) acc[i][j] = (float4v){0.f, 0.f, 0.f, 0.f};

  for (int k0 = 0; k0 < D_MODEL; k0 += 64) {
    // stage A (x) and B (weights): 128 rows x 64 k each, swizzled source
#pragma unroll
    for (int it = 0; it < 4; ++it) {
      const int idx = it * 256 + t;  // 0..1023
      const int r   = idx >> 3;
      const int s   = idx & 7;
      const int ko  = k0 + ((s ^ (r & 7)) << 3);
      gld_lds16(xb  + (size_t)(a0 + r) * D_MODEL + ko, &As[idx * 8]);
      gld_lds16(Wgt + (size_t)(b0 + r) * D_MODEL + ko, &Bs[idx * 8]);
    }
    __syncthreads();

#pragma unroll
    for (int kc = 0; kc < 2; ++kc) {
      const int slot = ((kc * 4 + q) ^ sw) * 8;
      short8 af[4], bf[4];
      // A-operand: Q-path -> weights (Bs); V-path -> activations (As)
#pragma unroll
      for (int i = 0; i < 4; ++i)
        af[i] = *(const short8*)&(vt ? As : Bs)[(wr * 64 + i * 16 + c) * 64 + slot];
#pragma unroll
      for (int j = 0; j < 4; ++j)
        bf[j] = *(const short8*)&(vt ? Bs : As)[(wc * 64 + j * 16 + c) * 64 + slot];
#pragma unroll
      for (int i = 0; i < 4; ++i)
#pragma unroll
        for (int j = 0; j < 4; ++j)
          acc[i][j] = __builtin_amdgcn_mfma_f32_16x16x32_bf16(af[i], bf[j], acc[i][j], 0, 0, 0);
    }
    __syncthreads();
  }

  if (!vt) {
    // Q (swapped): acc[i][j][tt] = Q[a0 + wc*64 + j*16 + c][nt*128 + wr*64 + i*16 + 4q + tt]
#pragma unroll
    for (int j = 0; j < 4; ++j) {
      const size_t row = a0 + wc * 64 + j * 16 + c;
#pragma unroll
      for (int i = 0; i < 4; ++i) {
        uint2 pkt;
        pkt.x = (unsigned)bf16r(scale * acc[i][j][0]) |
                ((unsigned)bf16r(scale * acc[i][j][1]) << 16);
        pkt.y = (unsigned)bf16r(scale * acc[i][j][2]) |
                ((unsigned)bf16r(scale * acc[i][j][3]) << 16);
        *(uint2*)&Qb[row * D_MODEL + nt * 128 + wr * 64 + i * 16 + 4 * q] = pkt;
      }
    }
  } else {
    // V (unswapped): acc[i][j][tt] = V[key = a0 + wr*64 + i*16 + 4q + tt][dim]
#pragma unroll
    for (int j = 0; j < 4; ++j) {
      const int dim = (nt - 4) * 128 + wc * 64 + j * 16 + c;
      const float bvv = bv[dim];
#pragma unroll
      for (int i = 0; i < 4; ++i) {
        const int key = a0 + wr * 64 + i * 16 + 4 * q;
        uint2 pkt;
        pkt.x = (unsigned)bf16r(acc[i][j][0] + bvv) |
                ((unsigned)bf16r(acc[i][j][1] + bvv) << 16);
        pkt.y = (unsigned)bf16r(acc[i][j][2] + bvv) |
                ((unsigned)bf16r(acc[i][j][3] + bvv) << 16);
        *(uint2*)&Vt[(size_t)dim * BS + key] = pkt;
      }
    }
  }
}

// --------------------------------------------------------------------------
// Windowed causal ALiBi attention. Block = 128 threads (2 waves) = one
// 16-query tile; grid = 1024. Window = keys [i0-48, i0+15] (excluded mass
// <= ~3e-8 at bf16 tol). Chunk-0 V loads issued before the softmax phase
// (T14) so HBM latency drains under the reductions/barrier.
// --------------------------------------------------------------------------
__global__ __launch_bounds__(128) void attn_tile(const unsigned short* __restrict__ Q,
                                                 const unsigned short* __restrict__ Kx,
                                                 const unsigned short* __restrict__ Vt,
                                                 float* __restrict__ out) {
  constexpr int PLD = 72;  // 64 + 8 pad shorts; row stride 144 B (16B-aligned)
  __shared__ unsigned short pls[16 * PLD];  // 2304 B
  __shared__ float lm[2][16], ls[2][16];

  const int t    = threadIdx.x;
  const int h    = t >> 6;
  const int lane = t & 63;
  const int q    = lane >> 4;
  const int c    = lane & 15;

  // XCD-contiguous swizzle: XCD x gets tiles [x*128, (x+1)*128)
  const int tile = ((blockIdx.x & 7) << 7) + (blockIdx.x >> 3);
  const int r0   = tile << 4;           // global query base
  const int b    = r0 >> 12;            // batch
  const int i0   = r0 & (SEQ - 1);      // local query base
  const int jb   = i0 - 48;             // window start (may be < 0)

  // ---- Q fragments: 16 queries x 512 (both waves load the same Q) ----
  short8 qf[16];
  {
    const unsigned short* qp = Q + (size_t)(r0 + c) * D_MODEL + q * 8;
#pragma unroll
    for (int ch = 0; ch < 16; ++ch) qf[ch] = *(const short8*)(qp + ch * 32);
  }

  // ---- S = Q K^T for this wave's 2 subtiles (sj = 2h, 2h+1) ----
  float4v sacc[2];
  sacc[0] = (float4v){0.f, 0.f, 0.f, 0.f};
  sacc[1] = (float4v){0.f, 0.f, 0.f, 0.f};
#pragma unroll
  for (int s = 0; s < 2; ++s) {
    const int sj = 2 * h + s;
    if (jb + 16 * sj + 15 < 0) continue;  // whole subtile below key 0
    int krow = jb + 16 * sj + c;
    if (krow < 0) krow = 0;  // masked below
    const unsigned short* kr = Kx + ((size_t)(b << 12) + krow) * D_MODEL + q * 8;
    float4v sv = sacc[s];
#pragma unroll
    for (int ch = 0; ch < 16; ++ch)
      sv = __builtin_amdgcn_mfma_f32_16x16x32_bf16(qf[ch], *(const short8*)(kr + ch * 32), sv, 0, 0, 0);
    sacc[s] = sv;
  }

  // ---- prefetch V chunk 0 (latency hides under softmax reductions) ----
  const unsigned short* vbase = Vt + (size_t)(h * 256 + c) * BS + (b << 12);
  const bool ch0 = (jb + 31 >= 0);
  short8 vf0[16];
  if (ch0) {
    int kk = jb + q * 8;
    if (kk < 0) kk = 0;  // p == 0 there
    const unsigned short* vb = vbase + kk;
#pragma unroll
    for (int dt = 0; dt < 16; ++dt) vf0[dt] = *(const short8*)(vb + (size_t)dt * 16 * BS);
  }

  // ---- ALiBi + causal/window mask + wave-local row max ----
  float tmax[4] = {-1e30f, -1e30f, -1e30f, -1e30f};
#pragma unroll
  for (int s = 0; s < 2; ++s)
#pragma unroll
    for (int tt = 0; tt < 4; ++tt) {
      const int jl = jb + 16 * (2 * h + s) + c;
      const int il = i0 + 4 * q + tt;
      float sv = sacc[s][tt];
      sv = (jl < 0 || jl > il) ? -1e30f : sv + 0.5f * (float)(jl - il);
      sacc[s][tt] = sv;
      tmax[tt] = fmaxf(tmax[tt], sv);
    }
#pragma unroll
  for (int tt = 0; tt < 4; ++tt) {
    float v = tmax[tt];
    v = fmaxf(v, __shfl_xor(v, 1, 64));
    v = fmaxf(v, __shfl_xor(v, 2, 64));
    v = fmaxf(v, __shfl_xor(v, 4, 64));
    v = fmaxf(v, __shfl_xor(v, 8, 64));
    tmax[tt] = v;
  }
  if (c == 0) {
#pragma unroll
    for (int tt = 0; tt < 4; ++tt) lm[h][4 * q + tt] = tmax[tt];
  }
  __syncthreads();  // 2-wave barrier (also drains vf0 prefetch)

  // ---- global max, p = exp(s-m), P -> LDS, partial sums ----
  float m[4];
#pragma unroll
  for (int tt = 0; tt < 4; ++tt)
    m[tt] = fmaxf(lm[0][4 * q + tt], lm[1][4 * q + tt]);

  float rsum[4] = {0.f, 0.f, 0.f, 0.f};
#pragma unroll
  for (int s = 0; s < 2; ++s)
#pragma unroll
    for (int tt = 0; tt < 4; ++tt) {
      const float p = __expf(sacc[s][tt] - m[tt]);
      rsum[tt] += p;
      pls[(4 * q + tt) * PLD + (2 * h + s) * 16 + c] = bf16r(p);
    }
#pragma unroll
  for (int tt = 0; tt < 4; ++tt) {
    float v = rsum[tt];
    v += __shfl_xor(v, 1, 64);
    v += __shfl_xor(v, 2, 64);
    v += __shfl_xor(v, 4, 64);
    v += __shfl_xor(v, 8, 64);
    rsum[tt] = v;
  }
  if (c == 0) {
#pragma unroll
    for (int tt = 0; tt < 4; ++tt) ls[h][4 * q + tt] = rsum[tt];
  }
  __syncthreads();  // 2-wave barrier

  float l[4];
#pragma unroll
  for (int tt = 0; tt < 4; ++tt)
    l[tt] = ls[0][4 * q + tt] + ls[1][4 * q + tt];

  // ---- O = P V for D-half h (dims h*256 .. +255), 64 keys ----
  float4v oacc[16];
#pragma unroll
  for (int dt = 0; dt < 16; ++dt) oacc[dt] = (float4v){0.f, 0.f, 0.f, 0.f};

  // chunk 0: V already resident in vf0
  if (ch0) {
    const short8 pa = *(const short8*)&pls[c * PLD + q * 8];
#pragma unroll
    for (int dt = 0; dt < 16; ++dt)
      oacc[dt] = __builtin_amdgcn_mfma_f32_16x16x32_bf16(pa, vf0[dt], oacc[dt], 0, 0, 0);
  }
  // chunk 1: loads overlap chunk-0 MFMAs (no barrier between)
  {
    const short8 pa = *(const short8*)&pls[c * PLD + 32 + q * 8];
    int kk = jb + 32 + q * 8;
    if (kk < 0) kk = 0;  // p == 0 there
    const unsigned short* vb = vbase + kk;
#pragma unroll
    for (int dt = 0; dt < 16; ++dt) {
      const short8 vf = *(const short8*)(vb + (size_t)dt * 16 * BS);
      oacc[dt] = __builtin_amdgcn_mfma_f32_16x16x32_bf16(pa, vf, oacc[dt], 0, 0, 0);
    }
  }

  // ---- epilogue: O / l ----
  float inv[4];
#pragma unroll
  for (int tt = 0; tt < 4; ++tt) inv[tt] = 1.0f / l[tt];
#pragma unroll
  for (int dt = 0; dt < 16; ++dt)
#pragma unroll
    for (int tt = 0; tt < 4; ++tt)
      out[(size_t)(r0 + 4 * q + tt) * D_MODEL + h * 256 + dt * 16 + c] =
          oacc[dt][tt] * inv[tt];
}

// --------------------------------------------------------------------------
extern "C" void kernel_launch(void* const* d_in, const int* in_sizes, int n_in,
                              void* d_out, int out_size, void* d_ws,
                              size_t ws_size, hipStream_t stream) {
  const float* x   = (const float*)d_in[0];
  const float* Wqk = (const float*)d_in[1];
  const float* Wv  = (const float*)d_in[2];
  const float* bv  = (const float*)d_in[3];
  float* out = (float*)d_out;

  unsigned short* xb   = (unsigned short*)d_ws;                  // 16 MB
  unsigned short* Qb   = xb + (size_t)BS * D_MODEL;              // 16 MB
  unsigned short* Vt   = Qb + (size_t)BS * D_MODEL;              // 16 MB
  unsigned short* Wqkt = Vt + (size_t)BS * D_MODEL;              // 512 KB
  unsigned short* Wvb  = Wqkt + (size_t)D_MODEL * D_MODEL;       // 512 KB

  const float scale = 1.0f / sqrtf((float)D_MODEL);

  cvt_w<<<dim3(192 + (BS * D_MODEL / 2048)), dim3(256), 0, stream>>>(Wqk, Wqkt, Wv, Wvb, x, xb);
  qv_gemm<<<dim3(1024), dim3(256), 0, stream>>>(xb, Wqkt, Wvb, bv, Qb, Vt, scale);
  attn_tile<<<dim3(BS / 16), dim3(128), 0, stream>>>(Qb, xb, Vt, out);
}